// Round 9
// baseline (228.580 us; speedup 1.0000x reference)
//
#include <hip/hip_runtime.h>
#include <math.h>

#define NN 100000
#define NE 600000
#define CAP 32          // bucket capacity/node; P(Poisson(6) >= 32) ~ 1e-15
#define GN 391          // ceil(NN/256)
#define GEMM1B 3125     // NN/32 exact -- gemm1: 32 nodes/block
#define AGB 6250        // NN/16 exact -- agg_gemm: 16 nodes/block
#define FILLB 2344      // ceil(NE/256)
// D = 128 fixed

typedef unsigned short u16;
typedef unsigned long long u64;
typedef __attribute__((ext_vector_type(8))) short bf16x8;
typedef __attribute__((ext_vector_type(4))) float f32x4;
typedef __attribute__((ext_vector_type(2))) float f32x2;

union U16x8 { uint4 u; bf16x8 h; };

__device__ __forceinline__ float bflo(unsigned w) { return __uint_as_float(w << 16); }
__device__ __forceinline__ float bfhi(unsigned w) { return __uint_as_float(w & 0xFFFF0000u); }
__device__ __forceinline__ u16 f2bf(float f) {  // round-to-nearest-even
    unsigned u = __float_as_uint(f);
    return (u16)((u + 0x7FFFu + ((u >> 16) & 1u)) >> 16);
}
__device__ __forceinline__ unsigned pack2(float a, float b) {
    return (unsigned)f2bf(a) | ((unsigned)f2bf(b) << 16);
}
__device__ __forceinline__ f32x2 unpk2(unsigned u) {
    f32x2 r; r.x = __uint_as_float(u << 16); r.y = __uint_as_float(u & 0xFFFF0000u);
    return r;
}
// bucket entry: src(17b) << 15 | bf16-weight[14:0] (sign always 0 for ew in [0,1])
__device__ __forceinline__ float bfw(unsigned e) {
    return __uint_as_float((e & 0x7FFFu) << 16);
}
__device__ __forceinline__ int ld_idx(const int* __restrict__ ei, unsigned is32, int pos) {
    return is32 ? ei[pos] : ei[2 * pos];  // int64: little-endian low word
}

// ---------- pair-gather aggregate (R8/R9) ----------
// Wave = 2 groups of 32 lanes; lane g*32+c32 loads uint2 (4 channels) of group-g's
// edge -> ONE VMEM instruction gathers TWO edges (class-8 node: 6 issues vs 10).
// Weights: 2 readlanes (SALU) + per-lane cndmask select on g. After the slot loop,
// 4x shfl_xor(32) merges groups; BOTH halves then hold identical full channel sums
// -> divergence-free epilogue. c is wave-uniform -> scalar class dispatch NP=2/4/6
// pairs (P(c<=4)=.285, P(c<=8)=.847, P(c>12)=.009); invalid slots gather the hot
// self row (L1 hit). All NP loads issue before any fma.
// R9 FIX: self row must be seeded into ONE group only (R8 seeded both -> the
// shfl_xor merge double-counted H[n]; absmax 4.2 = one extra dinv*H[n]).
template<int NP, bool TAIL>
__device__ __forceinline__ void agg_pairs(const uint2* __restrict__ H2r,
                                          unsigned entry, int c, unsigned n,
                                          int c32, int g, f32x2& a01, f32x2& a23)
{
    uint2 uu[NP];
    float ww[NP];
#pragma unroll
    for (int p = 0; p < NP; ++p) {
        unsigned e0 = (unsigned)__builtin_amdgcn_readlane((int)entry, 2 * p);
        unsigned e1 = (unsigned)__builtin_amdgcn_readlane((int)entry, 2 * p + 1);
        unsigned eg = g ? e1 : e0;              // v_cndmask on lane group
        bool vg = (2 * p + g) < c;
        ww[p] = vg ? bfw(eg) : 0.f;
        unsigned src = vg ? (eg >> 15) : n;     // invalid -> hot self row
        uu[p] = H2r[(size_t)src * 32u + c32];
    }
#pragma unroll
    for (int p = 0; p < NP; ++p) {
        f32x2 wv; wv.x = ww[p]; wv.y = ww[p];
        a01 = __builtin_elementwise_fma(unpk2(uu[p].x), wv, a01);
        a23 = __builtin_elementwise_fma(unpk2(uu[p].y), wv, a23);
    }
    if (TAIL && 2 * NP + g < c) {               // rare (~0.9% of nodes)
        for (int p = NP; 2 * p + g < c; ++p) {
            unsigned e0 = (unsigned)__builtin_amdgcn_readlane((int)entry, 2 * p);
            unsigned e1 = (unsigned)__builtin_amdgcn_readlane((int)entry, 2 * p + 1);
            unsigned eg = g ? e1 : e0;
            f32x2 wv; wv.x = bfw(eg); wv.y = wv.x;
            uint2 u = H2r[(size_t)(eg >> 15) * 32u + c32];
            a01 = __builtin_elementwise_fma(unpk2(u.x), wv, a01);
            a23 = __builtin_elementwise_fma(unpk2(u.y), wv, a23);
        }
    }
}
__device__ __forceinline__ void agg_dispatch2(const uint2* __restrict__ H2r,
                                              unsigned entry, int c, unsigned n,
                                              int c32, int g, f32x2& a01, f32x2& a23)
{
    if (c <= 4)      agg_pairs<2, false>(H2r, entry, c, n, c32, g, a01, a23);
    else if (c <= 8) agg_pairs<4, false>(H2r, entry, c, n, c32, g, a01, a23);
    else             agg_pairs<6, true >(H2r, entry, c, n, c32, g, a01, a23);
}

// ---------- W -> bf16 fragment-order block (8 blocks of 256 thr per W) ----------
// Tile (ct,kc): lane holds W[kc*32+(lane>>4)*8+j][ct*16+(lane&15)], j=0..7.
__device__ __forceinline__ void wconv_block(const float* __restrict__ W, u16* __restrict__ Wf,
                                            int blk, int tid) {
    int t = blk * 256 + tid;   // 0..2047
    int lane = t & 63, tile = t >> 6;
    int n = (tile >> 2) * 16 + (lane & 15);
    int k0 = (tile & 3) * 32 + (lane >> 4) * 8;
#pragma unroll
    for (int j = 0; j < 8; ++j) Wf[tile * 512 + lane * 8 + j] = f2bf(W[(k0 + j) * 128 + n]);
}

// ---------- init: zero cursor | detect int32-vs-int64 | wconv W1/W2 ----------
__global__ __launch_bounds__(256) void init_kernel(
    int* __restrict__ cursor, unsigned* __restrict__ flag, const unsigned* __restrict__ ei,
    const float* __restrict__ W1, const float* __restrict__ W2,
    u16* __restrict__ Wf1, u16* __restrict__ Wf2)
{
    __shared__ unsigned red[256];
    int b = blockIdx.x, tid = threadIdx.x;
    if (b < GN) {
        int i = b * 256 + tid;
        if (i < NN) cursor[i] = 0;
    } else if (b == GN) {
        unsigned v = 0;
        for (int i = tid; i < 4096; i += 256) v |= ei[2 * i + 1];
        red[tid] = v;
        __syncthreads();
        for (int o = 128; o > 0; o >>= 1) {
            if (tid < o) red[tid] |= red[tid + o];
            __syncthreads();
        }
        if (tid == 0) *flag = red[0] ? 1u : 0u;   // nonzero -> int32 storage
    } else if (b <= GN + 8) {
        wconv_block(W1, Wf1, b - GN - 1, tid);
    } else {
        wconv_block(W2, Wf2, b - GN - 9, tid);
    }
}

// ---------- fill: ONE u32 cursor atomic per edge + 4B bucket store ----------
// Runs ALONE: its cursor/bucket working set must own the L2 (r7/r12 lesson).
// ~40 us = device returning-atomic throughput floor (probed 1/thread, 2/thread, fused).
__global__ __launch_bounds__(256) void fill_kernel(
    const int* __restrict__ ei, const unsigned* __restrict__ flag,
    const float* __restrict__ ew, int* __restrict__ cursor, unsigned* __restrict__ bucket)
{
    int e = blockIdx.x * 256 + threadIdx.x;
    if (e < NE) {
        unsigned is32 = *flag;
        int s = ld_idx(ei, is32, e);
        int d = ld_idx(ei, is32, NE + e);
        unsigned wq = (unsigned)f2bf(ew[e]) & 0x7FFFu;   // bf16, sign bit 0
        int slot = atomicAdd(&cursor[d], 1);
        if (slot < CAP) bucket[(size_t)d * CAP + slot] = ((unsigned)s << 15) | wq;
    }
}

// ---------- gemm1: fused unpack (dinv from buckets) + H1 = diag(dinv) * (X @ W1) ----------
// R7 geometry: 32 nodes/block (3125 blocks), wave w -> row-group (w>>1) x ct-tiles
// (w&1)*4..+3. Per-node Wf traffic 2KB (constant since R6). Grid divides NN exactly.
// Phase 0: 8 threads/node degree sum -> dinv + clamped cursor + LDS.
__global__ __launch_bounds__(256) void gemm1_kernel(
    const float* __restrict__ X, const u16* __restrict__ Wf, u16* __restrict__ H,
    int* __restrict__ cursor, const unsigned* __restrict__ bucket,
    float* __restrict__ dinv)
{
    __shared__ float Ldn[32];
    const int tid = threadIdx.x;
    const unsigned blockBase = blockIdx.x * 32u;

    {   // phase 0: weighted degree -> dinv (8 threads/node)
        unsigned ni = (unsigned)tid >> 3, p = (unsigned)tid & 7;
        unsigned gn = blockBase + ni;
        int c = cursor[gn];
        if (c > CAP) c = CAP;
        float s = 0.f;
        const size_t base = (size_t)gn * CAP;
        for (int i = (int)p; i < c; i += 8) s += bfw(bucket[base + i]);
        s += __shfl_xor(s, 1);
        s += __shfl_xor(s, 2);
        s += __shfl_xor(s, 4);
        if (p == 0) {
            cursor[gn] = c;                  // clamp for agg kernels
            float dv = rsqrtf(s + 1.0f);
            dinv[gn] = dv;
            Ldn[ni] = dv;
        }
    }
    __syncthreads();

    const int wave = tid >> 6, lane = tid & 63;
    const int m = lane & 15, q = lane >> 4;
    const unsigned g = (unsigned)wave >> 1;            // row group 0/1 (16 rows each)
    const unsigned ct0 = ((unsigned)wave & 1u) * 4u;   // ct tiles ct0..ct0+3
    const unsigned nodeBase = blockBase + g * 16u;

    U16x8 xf[4];
    float dn;
    {
        unsigned row = nodeBase + m;                   // always < NN (exact grid)
        dn = Ldn[row - blockBase];
#pragma unroll
        for (int kc = 0; kc < 4; ++kc) {
            float4 a = ((const float4*)X)[row * 32u + kc * 8 + q * 2];
            float4 b = ((const float4*)X)[row * 32u + kc * 8 + q * 2 + 1];
            xf[kc].u = make_uint4(pack2(a.x, a.y), pack2(a.z, a.w),
                                  pack2(b.x, b.y), pack2(b.z, b.w));
        }
    }

    unsigned node = nodeBase + m;
#pragma unroll
    for (int ci = 0; ci < 4; ++ci) {
        unsigned ct = ct0 + ci;
        U16x8 wfr[4];
#pragma unroll
        for (int kc = 0; kc < 4; ++kc)
            wfr[kc].u = ((const uint4*)Wf)[(ct * 4 + kc) * 64 + lane];
        f32x4 acc = (f32x4){0.f, 0.f, 0.f, 0.f};
#pragma unroll
        for (int kc = 0; kc < 4; ++kc)
            acc = __builtin_amdgcn_mfma_f32_16x16x32_bf16(
                wfr[kc].h, xf[kc].h, acc, 0, 0, 0);
        uint2 o = make_uint2(pack2(acc[0] * dn, acc[1] * dn),
                             pack2(acc[2] * dn, acc[3] * dn));
        *(uint2*)&H[(size_t)node * 128 + ct * 16 + q * 4] = o;
    }
}

// ---------- agg_gemm: pair-gather aggregate -> LDS -> H2 = Xs @ W2 ----------
// R7 geometry (16 nodes/block, 4/wave, 6250 blocks); pair-gather (agg_dispatch2):
// 2 edges per VMEM instruction, 4 shfl_xor(32) merge, epilogue divergence-free:
// lane packs channels (2*(2*c32+g)..+1), LDS layout byte-identical to R7, MFMA
// read path untouched. Self row seeded in group 0 ONLY (R9 fix).
__global__ __launch_bounds__(256) void agg_gemm_kernel(
    const int* __restrict__ cnt, const unsigned* __restrict__ bucket,
    const u16* __restrict__ H, const float* __restrict__ dinv,
    const float* __restrict__ bias, const u16* __restrict__ Wf,
    u16* __restrict__ Hout)
{
    __shared__ unsigned Xs32[1024];   // 16 rows x 64 u32 = 4 KB
    const int tid = threadIdx.x;
    const int wave = tid >> 6, lane = tid & 63;
    const int c32 = lane & 31, gg = lane >> 5;
    const unsigned blockBase = blockIdx.x * 16u;
    const uint2* H2r = (const uint2*)H;

    float4 bias4 = ((const float4*)bias)[c32];    // channels 4*c32 .. +3

    const unsigned nb = blockBase + (unsigned)wave * 4u;
    unsigned lane_entry = bucket[nb * CAP + (unsigned)c32];
    int cpre = cnt[nb];
    float dpre = dinv[nb];

    for (int j = 0; j < 4; ++j) {
        unsigned n = nb + j;                 // always < NN (exact grid)
        unsigned entry = lane_entry;
        int c = cpre;
        float dnv = dpre;
        uint2 hn2 = H2r[(size_t)n * 32u + c32];
        if (j < 3) {   // prefetch next node's metadata (covers entry->gather dep)
            unsigned n1 = nb + j + 1;
            lane_entry = bucket[n1 * CAP + (unsigned)c32];
            cpre = cnt[n1];
            dpre = dinv[n1];
        }

        // R9 FIX: seed self row into group 0 only (merge would double-count)
        const f32x2 z2 = {0.f, 0.f};
        f32x2 a01 = gg ? z2 : unpk2(hn2.x);
        f32x2 a23 = gg ? z2 : unpk2(hn2.y);
        agg_dispatch2(H2r, entry, c, n, c32, gg, a01, a23);

        // merge groups: both halves end with identical full channel sums
        a01.x += __shfl_xor(a01.x, 32);
        a01.y += __shfl_xor(a01.y, 32);
        a23.x += __shfl_xor(a23.x, 32);
        a23.y += __shfl_xor(a23.y, 32);

        float v0 = fmaxf(fmaf(dnv, a01.x, bias4.x), 0.f);
        float v1 = fmaxf(fmaf(dnv, a01.y, bias4.y), 0.f);
        float v2 = fmaxf(fmaf(dnv, a23.x, bias4.z), 0.f);
        float v3 = fmaxf(fmaf(dnv, a23.y, bias4.w), 0.f);
        float va = gg ? v2 : v0, vb = gg ? v3 : v1;
        unsigned o = pack2(va * dnv, vb * dnv);       // X1' = relu(row)*dinv
        unsigned col = (unsigned)(c32 * 2 + gg);
        unsigned r = (unsigned)wave * 4u + (unsigned)j;
        Xs32[r * 64u + (((col >> 2) ^ (r & 7u)) << 2) + (col & 3u)] = o;
    }
    __syncthreads();   // MFMA reads other waves' rows

    const int m = lane & 15, q = lane >> 4;
    const unsigned ct0 = (unsigned)wave * 2u;          // ct tiles ct0, ct0+1
    U16x8 xf[4];
    {
        unsigned r = (unsigned)m;
#pragma unroll
        for (int kc = 0; kc < 4; ++kc)
            xf[kc].u = ((const uint4*)Xs32)[r * 16u + ((unsigned)(kc * 4 + q) ^ (r & 7u))];
    }
    unsigned node = blockBase + (unsigned)m;
#pragma unroll
    for (int ci = 0; ci < 2; ++ci) {
        unsigned ct = ct0 + ci;
        U16x8 wfr[4];
#pragma unroll
        for (int kc = 0; kc < 4; ++kc)
            wfr[kc].u = ((const uint4*)Wf)[(ct * 4 + kc) * 64 + lane];
        f32x4 acc = (f32x4){0.f, 0.f, 0.f, 0.f};
#pragma unroll
        for (int kc = 0; kc < 4; ++kc)
            acc = __builtin_amdgcn_mfma_f32_16x16x32_bf16(
                wfr[kc].h, xf[kc].h, acc, 0, 0, 0);
        uint2 o = make_uint2(pack2(acc[0], acc[1]), pack2(acc[2], acc[3]));
        *(uint2*)&Hout[(size_t)node * 128 + ct * 16 + q * 4] = o;
    }
}

// ---------- agg head: 1 wave/node, pair-gather + degree-class dispatch ----------
// out[n] = relu(dinv[n]*(sum w*H2[src] + H2[n]) + b2) . Wl + bl
// Self row seeded in group 0 only (R9 fix). After the merge both halves hold
// identical v[0..3] -> the 64-lane dot reduce yields 2x the dot; scale by 0.5f.
__global__ __launch_bounds__(256) void agg_head_kernel(
    const int* __restrict__ cnt, const unsigned* __restrict__ bucket,
    const u16* __restrict__ H, const float* __restrict__ dinv,
    const float* __restrict__ bias, const float* __restrict__ Wl,
    const float* __restrict__ bl, float* __restrict__ out)
{
    unsigned t = blockIdx.x * 256 + threadIdx.x;
    unsigned n = t >> 6;
    int lane = (int)(t & 63);
    const int c32 = lane & 31, gg = lane >> 5;
    const uint2* H2r = (const uint2*)H;

    unsigned entry = bucket[n * CAP + (unsigned)c32];
    const int c = cnt[n];
    uint2 hn2 = H2r[(size_t)n * 32u + c32];
    float dnv = dinv[n];

    // R9 FIX: seed self row into group 0 only
    const f32x2 z2 = {0.f, 0.f};
    f32x2 a01 = gg ? z2 : unpk2(hn2.x);
    f32x2 a23 = gg ? z2 : unpk2(hn2.y);
    agg_dispatch2(H2r, entry, c, n, c32, gg, a01, a23);

    a01.x += __shfl_xor(a01.x, 32);
    a01.y += __shfl_xor(a01.y, 32);
    a23.x += __shfl_xor(a23.x, 32);
    a23.y += __shfl_xor(a23.y, 32);

    float4 bias4 = ((const float4*)bias)[c32];
    float4 wl4   = ((const float4*)Wl)[c32];
    float v0 = fmaxf(fmaf(dnv, a01.x, bias4.x), 0.f);
    float v1 = fmaxf(fmaf(dnv, a01.y, bias4.y), 0.f);
    float v2 = fmaxf(fmaf(dnv, a23.x, bias4.z), 0.f);
    float v3 = fmaxf(fmaf(dnv, a23.y, bias4.w), 0.f);
    float d = v0 * wl4.x + v1 * wl4.y + v2 * wl4.z + v3 * wl4.w;
#pragma unroll
    for (int off = 32; off > 0; off >>= 1) d += __shfl_down(d, off);
    if (lane == 0) out[n] = fmaf(0.5f, d, bl[0]);
}

extern "C" void kernel_launch(void* const* d_in, const int* in_sizes, int n_in,
                              void* d_out, int out_size, void* d_ws, size_t ws_size,
                              hipStream_t stream) {
    const float* w_x = (const float*)d_in[0];
    const int*   ei  = (const int*)d_in[1];
    const float* ew  = (const float*)d_in[2];
    const float* W1  = (const float*)d_in[3];
    const float* b1  = (const float*)d_in[4];
    const float* W2  = (const float*)d_in[5];
    const float* b2  = (const float*)d_in[6];
    const float* Wl  = (const float*)d_in[7];
    const float* bl  = (const float*)d_in[8];
    float* out = (float*)d_out;

    // ws: H1[NN*128 bf16] H2[NN*128 bf16] flag(+pad) dinv[NN]
    //     cursor[NN] bucket[NN*CAP u32] Wf1/Wf2[16384 u16]   (~65 MB)
    u16*      H1   = (u16*)d_ws;
    u16*      H2   = H1 + (size_t)NN * 128;
    unsigned* flag = (unsigned*)(H2 + (size_t)NN * 128);
    float*    dinv = (float*)(flag + 2);
    int*      cursor = (int*)(dinv + NN);
    unsigned* bucket = (unsigned*)(cursor + NN);
    u16*      Wf1  = (u16*)(bucket + (size_t)NN * CAP);
    u16*      Wf2  = Wf1 + 16384;

    const int BLK = 256;
    const int GA  = NN * 64 / BLK;     // 25000 head-agg blocks

    init_kernel<<<GN + 17, BLK, 0, stream>>>(cursor, flag, (const unsigned*)ei,
                                             W1, W2, Wf1, Wf2);
    fill_kernel<<<FILLB, BLK, 0, stream>>>(ei, flag, ew, cursor, bucket);
    gemm1_kernel<<<GEMM1B, BLK, 0, stream>>>(w_x, Wf1, H1, cursor, bucket, dinv);
    agg_gemm_kernel<<<AGB, BLK, 0, stream>>>(cursor, bucket, H1, dinv, b1, Wf2, H2);
    agg_head_kernel<<<GA, BLK, 0, stream>>>(cursor, bucket, H2, dinv, b2, Wl, bl, out);
}

// Round 10
// 216.072 us; speedup vs baseline: 1.0579x; 1.0579x over previous
//
#include <hip/hip_runtime.h>
#include <math.h>

#define NN 100000
#define NE 600000
#define CAP 32          // bucket capacity/node; P(Poisson(6) >= 32) ~ 1e-15
#define GN 391          // ceil(NN/256)
#define GEMM1B 3125     // NN/32 exact -- gemm1: 32 nodes/block
#define AGB 6250        // NN/16 exact -- agg_gemm: 16 nodes/block
#define FILLB 2344      // ceil(NE/256)
// D = 128 fixed
// R10 = exact revert to R7 (best verified: 216.5us). R8/R9 pair-gather regressed
// (+12us: DS-pipe shuffles + merge sync in the dependent chain); R4 manual pipeline
// regressed (+6us: VGPR pressure). The R7 structure -- compiler-scheduled readlane
// gather, degree-class dispatch, max TLP geometry -- is the measured optimum.

typedef unsigned short u16;
typedef unsigned long long u64;
typedef __attribute__((ext_vector_type(8))) short bf16x8;
typedef __attribute__((ext_vector_type(4))) float f32x4;
typedef __attribute__((ext_vector_type(2))) float f32x2;

union U16x8 { uint4 u; bf16x8 h; };

__device__ __forceinline__ float bflo(unsigned w) { return __uint_as_float(w << 16); }
__device__ __forceinline__ float bfhi(unsigned w) { return __uint_as_float(w & 0xFFFF0000u); }
__device__ __forceinline__ u16 f2bf(float f) {  // round-to-nearest-even
    unsigned u = __float_as_uint(f);
    return (u16)((u + 0x7FFFu + ((u >> 16) & 1u)) >> 16);
}
__device__ __forceinline__ unsigned pack2(float a, float b) {
    return (unsigned)f2bf(a) | ((unsigned)f2bf(b) << 16);
}
__device__ __forceinline__ f32x2 unpk2(unsigned u) {
    f32x2 r; r.x = __uint_as_float(u << 16); r.y = __uint_as_float(u & 0xFFFF0000u);
    return r;
}
// bucket entry: src(17b) << 15 | bf16-weight[14:0] (sign always 0 for ew in [0,1])
__device__ __forceinline__ float bfw(unsigned e) {
    return __uint_as_float((e & 0x7FFFu) << 16);
}
__device__ __forceinline__ int ld_idx(const int* __restrict__ ei, unsigned is32, int pos) {
    return is32 ? ei[pos] : ei[2 * pos];  // int64: little-endian low word
}

// ---------- degree-class aggregate body (R6) ----------
// c is wave-uniform -> callers branch SCALAR-ly into NS=4/8/12 straight-line bodies:
// E[slots issued] 13 -> ~8.5 (P(c<=4)=.285, P(c<=8)=.847, P(c>12)=.009). Invalid
// slots (i>=c) gather the already-hot self row (L1 hit) -- only within-class waste.
// All NS loads issue before any fma (latency batching preserved within class).
template<int NS, bool TAIL>
__device__ __forceinline__ f32x2 agg_rows(const unsigned* __restrict__ H32,
                                          unsigned entry, int c, unsigned ncl,
                                          int lane, unsigned hn)
{
    unsigned uu[NS];
    float ww[NS];
#pragma unroll
    for (int i = 0; i < NS; ++i) {
        unsigned e = (unsigned)__builtin_amdgcn_readlane((int)entry, i);
        bool val = i < c;
        ww[i] = val ? bfw(e) : 0.f;
        unsigned src = val ? (e >> 15) : ncl;
        uu[i] = H32[(size_t)src * 64u + lane];
    }
    f32x2 acc = unpk2(hn);
#pragma unroll
    for (int i = 0; i < NS; ++i) {
        f32x2 wv; wv.x = ww[i]; wv.y = ww[i];
        acc = __builtin_elementwise_fma(unpk2(uu[i]), wv, acc);
    }
    if (TAIL && c > NS) {             // rare (~0.9% of nodes)
        for (int i = NS; i < c; ++i) {
            unsigned e = (unsigned)__builtin_amdgcn_readlane((int)entry, i);
            f32x2 wv; wv.x = bfw(e); wv.y = wv.x;
            unsigned u = H32[(size_t)(e >> 15) * 64u + lane];
            acc = __builtin_elementwise_fma(unpk2(u), wv, acc);
        }
    }
    return acc;
}
__device__ __forceinline__ f32x2 agg_dispatch(const unsigned* __restrict__ H32,
                                              unsigned entry, int c, unsigned ncl,
                                              int lane, unsigned hn)
{
    if (c <= 4)  return agg_rows<4, false>(H32, entry, c, ncl, lane, hn);
    if (c <= 8)  return agg_rows<8, false>(H32, entry, c, ncl, lane, hn);
    return agg_rows<12, true>(H32, entry, c, ncl, lane, hn);
}

// ---------- W -> bf16 fragment-order block (8 blocks of 256 thr per W) ----------
// Tile (ct,kc): lane holds W[kc*32+(lane>>4)*8+j][ct*16+(lane&15)], j=0..7.
__device__ __forceinline__ void wconv_block(const float* __restrict__ W, u16* __restrict__ Wf,
                                            int blk, int tid) {
    int t = blk * 256 + tid;   // 0..2047
    int lane = t & 63, tile = t >> 6;
    int n = (tile >> 2) * 16 + (lane & 15);
    int k0 = (tile & 3) * 32 + (lane >> 4) * 8;
#pragma unroll
    for (int j = 0; j < 8; ++j) Wf[tile * 512 + lane * 8 + j] = f2bf(W[(k0 + j) * 128 + n]);
}

// ---------- init: zero cursor | detect int32-vs-int64 | wconv W1/W2 ----------
__global__ __launch_bounds__(256) void init_kernel(
    int* __restrict__ cursor, unsigned* __restrict__ flag, const unsigned* __restrict__ ei,
    const float* __restrict__ W1, const float* __restrict__ W2,
    u16* __restrict__ Wf1, u16* __restrict__ Wf2)
{
    __shared__ unsigned red[256];
    int b = blockIdx.x, tid = threadIdx.x;
    if (b < GN) {
        int i = b * 256 + tid;
        if (i < NN) cursor[i] = 0;
    } else if (b == GN) {
        unsigned v = 0;
        for (int i = tid; i < 4096; i += 256) v |= ei[2 * i + 1];
        red[tid] = v;
        __syncthreads();
        for (int o = 128; o > 0; o >>= 1) {
            if (tid < o) red[tid] |= red[tid + o];
            __syncthreads();
        }
        if (tid == 0) *flag = red[0] ? 1u : 0u;   // nonzero -> int32 storage
    } else if (b <= GN + 8) {
        wconv_block(W1, Wf1, b - GN - 1, tid);
    } else {
        wconv_block(W2, Wf2, b - GN - 9, tid);
    }
}

// ---------- fill: ONE u32 cursor atomic per edge + 4B bucket store ----------
// Runs ALONE: its cursor/bucket working set must own the L2 (r7/r12 lesson).
// ~40 us = device returning-atomic throughput floor (probed 1/thread, 2/thread, fused).
__global__ __launch_bounds__(256) void fill_kernel(
    const int* __restrict__ ei, const unsigned* __restrict__ flag,
    const float* __restrict__ ew, int* __restrict__ cursor, unsigned* __restrict__ bucket)
{
    int e = blockIdx.x * 256 + threadIdx.x;
    if (e < NE) {
        unsigned is32 = *flag;
        int s = ld_idx(ei, is32, e);
        int d = ld_idx(ei, is32, NE + e);
        unsigned wq = (unsigned)f2bf(ew[e]) & 0x7FFFu;   // bf16, sign bit 0
        int slot = atomicAdd(&cursor[d], 1);
        if (slot < CAP) bucket[(size_t)d * CAP + slot] = ((unsigned)s << 15) | wq;
    }
}

// ---------- gemm1: fused unpack (dinv from buckets) + H1 = diag(dinv) * (X @ W1) ----------
// R7 geometry: 32 nodes/block (3125 blocks), wave w -> row-group (w>>1) x ct-tiles
// (w&1)*4..+3. Per-node Wf traffic 2KB (constant since R6). Grid divides NN exactly.
// Phase 0: 8 threads/node degree sum -> dinv + clamped cursor + LDS.
__global__ __launch_bounds__(256) void gemm1_kernel(
    const float* __restrict__ X, const u16* __restrict__ Wf, u16* __restrict__ H,
    int* __restrict__ cursor, const unsigned* __restrict__ bucket,
    float* __restrict__ dinv)
{
    __shared__ float Ldn[32];
    const int tid = threadIdx.x;
    const unsigned blockBase = blockIdx.x * 32u;

    {   // phase 0: weighted degree -> dinv (8 threads/node)
        unsigned ni = (unsigned)tid >> 3, p = (unsigned)tid & 7;
        unsigned gn = blockBase + ni;
        int c = cursor[gn];
        if (c > CAP) c = CAP;
        float s = 0.f;
        const size_t base = (size_t)gn * CAP;
        for (int i = (int)p; i < c; i += 8) s += bfw(bucket[base + i]);
        s += __shfl_xor(s, 1);
        s += __shfl_xor(s, 2);
        s += __shfl_xor(s, 4);
        if (p == 0) {
            cursor[gn] = c;                  // clamp for agg kernels
            float dv = rsqrtf(s + 1.0f);
            dinv[gn] = dv;
            Ldn[ni] = dv;
        }
    }
    __syncthreads();

    const int wave = tid >> 6, lane = tid & 63;
    const int m = lane & 15, q = lane >> 4;
    const unsigned g = (unsigned)wave >> 1;            // row group 0/1 (16 rows each)
    const unsigned ct0 = ((unsigned)wave & 1u) * 4u;   // ct tiles ct0..ct0+3
    const unsigned nodeBase = blockBase + g * 16u;

    U16x8 xf[4];
    float dn;
    {
        unsigned row = nodeBase + m;                   // always < NN (exact grid)
        dn = Ldn[row - blockBase];
#pragma unroll
        for (int kc = 0; kc < 4; ++kc) {
            float4 a = ((const float4*)X)[row * 32u + kc * 8 + q * 2];
            float4 b = ((const float4*)X)[row * 32u + kc * 8 + q * 2 + 1];
            xf[kc].u = make_uint4(pack2(a.x, a.y), pack2(a.z, a.w),
                                  pack2(b.x, b.y), pack2(b.z, b.w));
        }
    }

    unsigned node = nodeBase + m;
#pragma unroll
    for (int ci = 0; ci < 4; ++ci) {
        unsigned ct = ct0 + ci;
        U16x8 wfr[4];
#pragma unroll
        for (int kc = 0; kc < 4; ++kc)
            wfr[kc].u = ((const uint4*)Wf)[(ct * 4 + kc) * 64 + lane];
        f32x4 acc = (f32x4){0.f, 0.f, 0.f, 0.f};
#pragma unroll
        for (int kc = 0; kc < 4; ++kc)
            acc = __builtin_amdgcn_mfma_f32_16x16x32_bf16(
                wfr[kc].h, xf[kc].h, acc, 0, 0, 0);
        uint2 o = make_uint2(pack2(acc[0] * dn, acc[1] * dn),
                             pack2(acc[2] * dn, acc[3] * dn));
        *(uint2*)&H[(size_t)node * 128 + ct * 16 + q * 4] = o;
    }
}

// ---------- agg_gemm: layer-1 aggregate (lane-local channels) -> LDS -> H2 = Xs @ W2 ----
// R7: 16 nodes/block (6250 blocks = 24 w/SIMD launched). Aggregate 4 nodes/wave; MFMA:
// each wave computes ALL 16 rows x 2 ct-tiles (ct = wave*2..+1). Per-node Wf traffic
// 2KB/node. LDS 4KB, VGPR ~28. Degree-class dispatch per R6. Grid divides NN exactly.
__global__ __launch_bounds__(256) void agg_gemm_kernel(
    const int* __restrict__ cnt, const unsigned* __restrict__ bucket,
    const u16* __restrict__ H, const float* __restrict__ dinv,
    const float* __restrict__ bias, const u16* __restrict__ Wf,
    u16* __restrict__ Hout)
{
    __shared__ unsigned Xs32[1024];   // 16 rows x 64 u32 = 4 KB
    const int tid = threadIdx.x;
    const int wave = tid >> 6, lane = tid & 63;
    const unsigned blockBase = blockIdx.x * 16u;
    const unsigned* H32 = (const unsigned*)H;

    float2 bias2 = ((const float2*)bias)[lane];   // channels 2*lane, 2*lane+1

    const unsigned nb = blockBase + (unsigned)wave * 4u;
    unsigned lane_entry = bucket[nb * CAP + (lane & 31)];
    int cpre = cnt[nb];
    float dpre = dinv[nb];

    for (int j = 0; j < 4; ++j) {
        unsigned n = nb + j;                 // always < NN (exact grid)
        unsigned entry = lane_entry;
        int c = cpre;
        float dnv = dpre;
        unsigned hn = H32[(size_t)n * 64u + lane];
        if (j < 3) {   // prefetch next node's metadata (covers entry->gather dep)
            unsigned n1 = nb + j + 1;
            lane_entry = bucket[n1 * CAP + (lane & 31)];
            cpre = cnt[n1];
            dpre = dinv[n1];
        }

        f32x2 acc = agg_dispatch(H32, entry, c, n, lane, hn);

        float vx = fmaxf(fmaf(dnv, acc.x, bias2.x), 0.f);
        float vy = fmaxf(fmaf(dnv, acc.y, bias2.y), 0.f);
        unsigned o = pack2(vx * dnv, vy * dnv);       // X1' = relu(row)*dinv, bf16x2
        unsigned r = (unsigned)wave * 4u + (unsigned)j;
        Xs32[r * 64u + ((((unsigned)lane >> 2) ^ (r & 7u)) << 2) + ((unsigned)lane & 3u)] = o;
    }
    __syncthreads();   // MFMA reads other waves' rows

    const int m = lane & 15, q = lane >> 4;
    const unsigned ct0 = (unsigned)wave * 2u;          // ct tiles ct0, ct0+1
    U16x8 xf[4];
    {
        unsigned r = (unsigned)m;
#pragma unroll
        for (int kc = 0; kc < 4; ++kc)
            xf[kc].u = ((const uint4*)Xs32)[r * 16u + ((unsigned)(kc * 4 + q) ^ (r & 7u))];
    }
    unsigned node = blockBase + (unsigned)m;
#pragma unroll
    for (int ci = 0; ci < 2; ++ci) {
        unsigned ct = ct0 + ci;
        U16x8 wfr[4];
#pragma unroll
        for (int kc = 0; kc < 4; ++kc)
            wfr[kc].u = ((const uint4*)Wf)[(ct * 4 + kc) * 64 + lane];
        f32x4 acc = (f32x4){0.f, 0.f, 0.f, 0.f};
#pragma unroll
        for (int kc = 0; kc < 4; ++kc)
            acc = __builtin_amdgcn_mfma_f32_16x16x32_bf16(
                wfr[kc].h, xf[kc].h, acc, 0, 0, 0);
        uint2 o = make_uint2(pack2(acc[0], acc[1]), pack2(acc[2], acc[3]));
        *(uint2*)&Hout[(size_t)node * 128 + ct * 16 + q * 4] = o;
    }
}

// ---------- agg head: 1 wave/node, lane-local channels + degree-class dispatch ----------
// out[n] = relu(dinv[n]*(sum w*H2[src] + H2[n]) + b2) . Wl + bl
__global__ __launch_bounds__(256) void agg_head_kernel(
    const int* __restrict__ cnt, const unsigned* __restrict__ bucket,
    const u16* __restrict__ H, const float* __restrict__ dinv,
    const float* __restrict__ bias, const float* __restrict__ Wl,
    const float* __restrict__ bl, float* __restrict__ out)
{
    unsigned t = blockIdx.x * 256 + threadIdx.x;
    unsigned n = t >> 6;
    int lane = (int)(t & 63);
    const unsigned* H32 = (const unsigned*)H;

    unsigned lane_entry = bucket[n * CAP + (lane & 31)];
    const int c = cnt[n];
    unsigned hn = H32[(size_t)n * 64u + lane];
    float dnv = dinv[n];

    f32x2 acc = agg_dispatch(H32, lane_entry, c, n, lane, hn);

    float2 bias2 = ((const float2*)bias)[lane];
    float2 wl2   = ((const float2*)Wl)[lane];
    float vx = fmaxf(fmaf(dnv, acc.x, bias2.x), 0.f);
    float vy = fmaxf(fmaf(dnv, acc.y, bias2.y), 0.f);
    float d = vx * wl2.x + vy * wl2.y;
#pragma unroll
    for (int off = 32; off > 0; off >>= 1) d += __shfl_down(d, off);
    if (lane == 0) out[n] = d + bl[0];
}

extern "C" void kernel_launch(void* const* d_in, const int* in_sizes, int n_in,
                              void* d_out, int out_size, void* d_ws, size_t ws_size,
                              hipStream_t stream) {
    const float* w_x = (const float*)d_in[0];
    const int*   ei  = (const int*)d_in[1];
    const float* ew  = (const float*)d_in[2];
    const float* W1  = (const float*)d_in[3];
    const float* b1  = (const float*)d_in[4];
    const float* W2  = (const float*)d_in[5];
    const float* b2  = (const float*)d_in[6];
    const float* Wl  = (const float*)d_in[7];
    const float* bl  = (const float*)d_in[8];
    float* out = (float*)d_out;

    // ws: H1[NN*128 bf16] H2[NN*128 bf16] flag(+pad) dinv[NN]
    //     cursor[NN] bucket[NN*CAP u32] Wf1/Wf2[16384 u16]   (~65 MB)
    u16*      H1   = (u16*)d_ws;
    u16*      H2   = H1 + (size_t)NN * 128;
    unsigned* flag = (unsigned*)(H2 + (size_t)NN * 128);
    float*    dinv = (float*)(flag + 2);
    int*      cursor = (int*)(dinv + NN);
    unsigned* bucket = (unsigned*)(cursor + NN);
    u16*      Wf1  = (u16*)(bucket + (size_t)NN * CAP);
    u16*      Wf2  = Wf1 + 16384;

    const int BLK = 256;
    const int GA  = NN * 64 / BLK;     // 25000 head-agg blocks

    init_kernel<<<GN + 17, BLK, 0, stream>>>(cursor, flag, (const unsigned*)ei,
                                             W1, W2, Wf1, Wf2);
    fill_kernel<<<FILLB, BLK, 0, stream>>>(ei, flag, ew, cursor, bucket);
    gemm1_kernel<<<GEMM1B, BLK, 0, stream>>>(w_x, Wf1, H1, cursor, bucket, dinv);
    agg_gemm_kernel<<<AGB, BLK, 0, stream>>>(cursor, bucket, H1, dinv, b1, Wf2, H2);
    agg_head_kernel<<<GA, BLK, 0, stream>>>(cursor, bucket, H2, dinv, b2, Wl, bl, out);
}